// Round 1
// baseline (716.263 us; speedup 1.0000x reference)
//
#include <hip/hip_runtime.h>
#include <math.h>

// Problem constants
#define TB 4
#define TS 2048
#define TE 1024
#define TH 16
#define TD 64
#define TM_ (TB*TS)   // 8192 rows

// Workspace float offsets
#define WS_Q   0
#define WS_K   8388608
#define WS_L   16777216
#define WS_TAB 16908288

typedef __attribute__((ext_vector_type(8))) short bf16x8;  // 8 bf16 = 4 VGPRs
typedef __attribute__((ext_vector_type(4))) float f32x4;

static __device__ inline unsigned fbits(float x) {
    union { float f; unsigned u; } v; v.f = x; return v.u;
}
static __device__ inline float bits2f(unsigned u) {
    union { unsigned u; float f; } v; v.u = u; return v.f;
}
// pack [bf16(a), bf16(b)] (round-half-up) into one dword, a in low half
static __device__ inline unsigned pack_rhu(float a, float b) {
    return __builtin_amdgcn_perm(fbits(b) + 0x8000u, fbits(a) + 0x8000u, 0x07060302u);
}
// hi/lo split of (x0,x1): hp = packed hi bf16s, lp = packed lo bf16s
static __device__ inline void split2(float x0, float x1, unsigned& hp, unsigned& lp) {
    unsigned u0 = fbits(x0) + 0x8000u, u1 = fbits(x1) + 0x8000u;
    hp = __builtin_amdgcn_perm(u1, u0, 0x07060302u);
    float h0 = bits2f(u0 & 0xffff0000u);
    float h1 = bits2f(u1 & 0xffff0000u);
    lp = pack_rhu(x0 - h0, x1 - h1);
}

// ----------------------------------------------------------------------------
// GEMM: C[m,n] = sum_k X[m,k] * W[n,k] + bias[n]
// R4: split-bf16 MFMA (3 terms: xh*wh + xl*wh + xh*wl ~ 16 mantissa bits)
// 128x128 tile, BK=32, 4 waves (2x2), mfma_f32_16x16x32_bf16.
// MODE 0: fp32 out[m*N+n];  MODE 1: fp32 [B,H,S,D];  MODE 2: bf16 V^T [B,H,D,S]
// ----------------------------------------------------------------------------
template<int MODE>
__global__ __launch_bounds__(256, 2)
void gemm_nt(const float* __restrict__ X, const float* __restrict__ W,
             const float* __restrict__ bias, float* __restrict__ out)
{
    // pad 32->40 shorts: row stride 80 B (16B-aligned, 2-way bank alias = free)
    __shared__ short Ah[128][40], Al[128][40];
    __shared__ short Bh[128][40], Bl[128][40];

    const int tid  = threadIdx.x;
    const int lane = tid & 63;
    const int wv   = tid >> 6;          // wave 0..3
    const int t16  = lane & 15;
    const int quad = lane >> 4;
    const int wm   = (wv >> 1) * 64;    // wave's m-offset within tile
    const int wn   = (wv & 1) * 64;     // wave's n-offset within tile
    const int m0 = blockIdx.y * 128;
    const int n0 = blockIdx.x * 128;
    const int K = TE, N = TE;

    // staging: thread -> (row = tid>>1, kchunk = (tid&1)*16) for both A and B
    const int srow = tid >> 1;
    const int skc  = (tid & 1) * 16;
    const float* Xp = X + (size_t)(m0 + srow) * K + skc;
    const float* Wp = W + (size_t)(n0 + srow) * K + skc;

    f32x4 acc[4][4];
    #pragma unroll
    for (int i = 0; i < 4; ++i)
        #pragma unroll
        for (int j = 0; j < 4; ++j) acc[i][j] = (f32x4){0.f, 0.f, 0.f, 0.f};

    for (int kt = 0; kt < K; kt += 32) {
        __syncthreads();   // previous iteration's frag reads complete
        // ---- stage A and B tiles: fp32 -> hi/lo bf16 ----
        {
            const float* xp = Xp + kt;
            float4 x0 = *(const float4*)(xp);
            float4 x1 = *(const float4*)(xp + 4);
            float4 x2 = *(const float4*)(xp + 8);
            float4 x3 = *(const float4*)(xp + 12);
            const float* wp = Wp + kt;
            float4 w0 = *(const float4*)(wp);
            float4 w1 = *(const float4*)(wp + 4);
            float4 w2 = *(const float4*)(wp + 8);
            float4 w3 = *(const float4*)(wp + 12);

            unsigned H[8], L[8];
            split2(x0.x, x0.y, H[0], L[0]);
            split2(x0.z, x0.w, H[1], L[1]);
            split2(x1.x, x1.y, H[2], L[2]);
            split2(x1.z, x1.w, H[3], L[3]);
            split2(x2.x, x2.y, H[4], L[4]);
            split2(x2.z, x2.w, H[5], L[5]);
            split2(x3.x, x3.y, H[6], L[6]);
            split2(x3.z, x3.w, H[7], L[7]);
            *(uint4*)&Ah[srow][skc]     = make_uint4(H[0], H[1], H[2], H[3]);
            *(uint4*)&Ah[srow][skc + 8] = make_uint4(H[4], H[5], H[6], H[7]);
            *(uint4*)&Al[srow][skc]     = make_uint4(L[0], L[1], L[2], L[3]);
            *(uint4*)&Al[srow][skc + 8] = make_uint4(L[4], L[5], L[6], L[7]);

            split2(w0.x, w0.y, H[0], L[0]);
            split2(w0.z, w0.w, H[1], L[1]);
            split2(w1.x, w1.y, H[2], L[2]);
            split2(w1.z, w1.w, H[3], L[3]);
            split2(w2.x, w2.y, H[4], L[4]);
            split2(w2.z, w2.w, H[5], L[5]);
            split2(w3.x, w3.y, H[6], L[6]);
            split2(w3.z, w3.w, H[7], L[7]);
            *(uint4*)&Bh[srow][skc]     = make_uint4(H[0], H[1], H[2], H[3]);
            *(uint4*)&Bh[srow][skc + 8] = make_uint4(H[4], H[5], H[6], H[7]);
            *(uint4*)&Bl[srow][skc]     = make_uint4(L[0], L[1], L[2], L[3]);
            *(uint4*)&Bl[srow][skc + 8] = make_uint4(L[4], L[5], L[6], L[7]);
        }
        __syncthreads();

        // ---- fragments and MFMA: 4x4 subtiles, 3 split terms ----
        bf16x8 ah[4], al[4], bh[4], bl[4];
        #pragma unroll
        for (int i = 0; i < 4; ++i) {
            ah[i] = *(const bf16x8*)&Ah[wm + i * 16 + t16][quad * 8];
            al[i] = *(const bf16x8*)&Al[wm + i * 16 + t16][quad * 8];
            bh[i] = *(const bf16x8*)&Bh[wn + i * 16 + t16][quad * 8];
            bl[i] = *(const bf16x8*)&Bl[wn + i * 16 + t16][quad * 8];
        }
        #pragma unroll
        for (int i = 0; i < 4; ++i)
            #pragma unroll
            for (int j = 0; j < 4; ++j) {
                acc[i][j] = __builtin_amdgcn_mfma_f32_16x16x32_bf16(ah[i], bh[j], acc[i][j], 0, 0, 0);
                acc[i][j] = __builtin_amdgcn_mfma_f32_16x16x32_bf16(al[i], bh[j], acc[i][j], 0, 0, 0);
                acc[i][j] = __builtin_amdgcn_mfma_f32_16x16x32_bf16(ah[i], bl[j], acc[i][j], 0, 0, 0);
            }
    }

    // ---- epilogue: C/D layout col = t16, row = quad*4 + r ----
    if (MODE == 2) {
        // bf16 V^T [B,H,D,S]: 4 consecutive s per lane -> one 8B store
        short* o16 = (short*)out;
        const int b = m0 >> 11;
        const int sbase0 = (m0 & 2047) + wm + quad * 4;
        #pragma unroll
        for (int j = 0; j < 4; ++j) {
            const int n = n0 + wn + j * 16 + t16;
            const int h = n >> 6, d = n & 63;
            const float bv = bias[n];
            const size_t base = ((size_t)(b * TH + h) * TD + d) * TS;
            #pragma unroll
            for (int i = 0; i < 4; ++i) {
                const int s = sbase0 + i * 16;
                uint2 p = make_uint2(pack_rhu(acc[i][j][0] + bv, acc[i][j][1] + bv),
                                     pack_rhu(acc[i][j][2] + bv, acc[i][j][3] + bv));
                *(uint2*)(o16 + base + s) = p;
            }
        }
        return;
    }

    #pragma unroll
    for (int j = 0; j < 4; ++j) {
        const int n = n0 + wn + j * 16 + t16;
        const float bv = bias[n];
        if (MODE == 0) {
            #pragma unroll
            for (int i = 0; i < 4; ++i)
                #pragma unroll
                for (int r = 0; r < 4; ++r) {
                    const int m = m0 + wm + i * 16 + quad * 4 + r;
                    out[(size_t)m * N + n] = acc[i][j][r] + bv;
                }
        } else {
            const int h = n >> 6, d = n & 63;
            #pragma unroll
            for (int i = 0; i < 4; ++i)
                #pragma unroll
                for (int r = 0; r < 4; ++r) {
                    const int m = m0 + wm + i * 16 + quad * 4 + r;
                    const int bb_ = m >> 11, s = m & 2047;
                    out[((size_t)(bb_ * TH + h) * TS + s) * TD + d] = acc[i][j][r] + bv;
                }
        }
    }
}

// ----------------------------------------------------------------------------
// RoPE (unchanged)
// ----------------------------------------------------------------------------
__global__ void rope_table(float* __restrict__ tab)
{
    const int idx = blockIdx.x * 256 + threadIdx.x;
    const int d = idx & 31, s = idx >> 5;
    const float e = (float)(2 * d) / 64.0f;
    const float inv = 1.0f / powf(10000.0f, e);
    const float a = (float)s * inv;
    tab[2 * idx + 0] = cosf(a);
    tab[2 * idx + 1] = sinf(a);
}

__global__ void rope_apply(float* __restrict__ Q, float* __restrict__ Kv,
                           const float* __restrict__ tab)
{
    const int idx = blockIdx.x * 256 + threadIdx.x;
    const int half = TB * TH * TS * 32;
    float* P = (idx < half) ? Q : Kv;
    const int u = idx & (half - 1);
    const int d = u & 31;
    const int s = (u >> 5) & 2047;
    const int bh = u >> 16;
    const size_t base = (size_t)bh * (TS * TD) + (size_t)s * TD;
    const float c  = tab[2 * (s * 32 + d) + 0];
    const float sn = tab[2 * (s * 32 + d) + 1];
    const float x0 = P[base + d], x1 = P[base + d + 32];
    P[base + d]      = x0 * c - x1 * sn;
    P[base + d + 32] = x1 * c + x0 * sn;
}

// ----------------------------------------------------------------------------
// Flash attention (unchanged from verified 1277 µs version)
// ----------------------------------------------------------------------------
__global__ __launch_bounds__(512, 4)
void attn_flash(const float* __restrict__ Q, const float* __restrict__ Kg,
                const short* __restrict__ VT, float* __restrict__ O,
                float* __restrict__ Ls)
{
    __shared__ short Kh[64][72], Kl[64][72];
    __shared__ short Vt[64][72];            // V^T tile: [d][j]
    __shared__ short Ps[128][72];           // P: [q][j]

    const int tid  = threadIdx.x;
    const int lane = tid & 63;
    const int wv   = tid >> 6;        // wave 0..7
    const int t16  = lane & 15;
    const int quad = lane >> 4;
    const int q0w  = wv * 16;         // wave's q-row base within 128-tile

    const int q0 = blockIdx.x * 128;
    const int h = blockIdx.y, b = blockIdx.z;
    const int bh = b * TH + h;
    const size_t hoff = (size_t)bh * TS * TD;
    const float* Kr = Kg + hoff;
    const short* Vth = VT + (size_t)bh * TD * TS;

    // ---- Q fragments straight from global, scaled by 0.125*log2(e), split ----
    const float qsc = 0.125f * 1.44269504f;
    bf16x8 qfh[2], qfl[2];
    {
        const float* qp = Q + hoff + (size_t)(q0 + q0w + t16) * TD;
        #pragma unroll
        for (int ks = 0; ks < 2; ++ks) {
            float4 a = *(const float4*)(qp + ks * 32 + quad * 8);
            float4 c = *(const float4*)(qp + ks * 32 + quad * 8 + 4);
            union { unsigned u[4]; bf16x8 v; } H, L;
            split2(a.x * qsc, a.y * qsc, H.u[0], L.u[0]);
            split2(a.z * qsc, a.w * qsc, H.u[1], L.u[1]);
            split2(c.x * qsc, c.y * qsc, H.u[2], L.u[2]);
            split2(c.z * qsc, c.w * qsc, H.u[3], L.u[3]);
            qfh[ks] = H.v; qfl[ks] = L.v;
        }
    }

    float lsum[4];
    f32x4 o_acc[4];
    #pragma unroll
    for (int r = 0; r < 4; ++r) lsum[r] = 0.f;
    #pragma unroll
    for (int dt = 0; dt < 4; ++dt) o_acc[dt] = (f32x4){0.f, 0.f, 0.f, 0.f};

    // staging indices (512 threads)
    const int krow = tid >> 3;           // 0..63
    const int kcol = (tid & 7) * 8;      // 0..56

    for (int j0 = 0; j0 < TS; j0 += 64) {
        __syncthreads();   // prev iter's Kh/Kl/Vt/Ps reads done
        // ---- stage K tile (fp32 -> hi/lo bf16), 8 elems per thread ----
        {
            const float* kp = Kr + (size_t)(j0 + krow) * TD + kcol;
            float4 a = *(const float4*)kp;
            float4 c = *(const float4*)(kp + 4);
            union { unsigned u[4]; } H, L;
            split2(a.x, a.y, H.u[0], L.u[0]);
            split2(a.z, a.w, H.u[1], L.u[1]);
            split2(c.x, c.y, H.u[2], L.u[2]);
            split2(c.z, c.w, H.u[3], L.u[3]);
            *(uint4*)&Kh[krow][kcol] = make_uint4(H.u[0], H.u[1], H.u[2], H.u[3]);
            *(uint4*)&Kl[krow][kcol] = make_uint4(L.u[0], L.u[1], L.u[2], L.u[3]);
            // ---- stage V^T tile (already bf16), 8 shorts per thread ----
            uint4 vv = *(const uint4*)(Vth + (size_t)krow * TS + j0 + kcol);
            *(uint4*)&Vt[krow][kcol] = vv;
        }
        __syncthreads();

        // ---- scores: 4 j-subtiles x 2 ksteps x 3 split terms ----
        f32x4 sc[4];
        #pragma unroll
        for (int t = 0; t < 4; ++t) sc[t] = (f32x4){0.f, 0.f, 0.f, 0.f};
        #pragma unroll
        for (int t = 0; t < 4; ++t) {
            #pragma unroll
            for (int ks = 0; ks < 2; ++ks) {
                bf16x8 kf_h = *(const bf16x8*)&Kh[t * 16 + t16][ks * 32 + quad * 8];
                bf16x8 kf_l = *(const bf16x8*)&Kl[t * 16 + t16][ks * 32 + quad * 8];
                sc[t] = __builtin_amdgcn_mfma_f32_16x16x32_bf16(qfh[ks], kf_h, sc[t], 0, 0, 0);
                sc[t] = __builtin_amdgcn_mfma_f32_16x16x32_bf16(qfh[ks], kf_l, sc[t], 0, 0, 0);
                sc[t] = __builtin_amdgcn_mfma_f32_16x16x32_bf16(qfl[ks], kf_h, sc[t], 0, 0, 0);
            }
        }

        // ---- p = exp2(s'), accumulate l, write P (bf16) to LDS ----
        #pragma unroll
        for (int t = 0; t < 4; ++t) {
            float p0 = __builtin_amdgcn_exp2f(sc[t][0]);
            float p1 = __builtin_amdgcn_exp2f(sc[t][1]);
            float p2 = __builtin_amdgcn_exp2f(sc[t][2]);
            float p3 = __builtin_amdgcn_exp2f(sc[t][3]);
            lsum[0] += p0; lsum[1] += p1; lsum[2] += p2; lsum[3] += p3;
            const int col = t * 16 + t16;
            Ps[q0w + quad * 4 + 0][col] = (short)(pack_rhu(p0, p0) & 0xffff);
            Ps[q0w + quad * 4 + 1][col] = (short)(pack_rhu(p1, p1) & 0xffff);
            Ps[q0w + quad * 4 + 2][col] = (short)(pack_rhu(p2, p2) & 0xffff);
            Ps[q0w + quad * 4 + 3][col] = (short)(pack_rhu(p3, p3) & 0xffff);
        }

        // ---- PV: o += P * V (intra-wave Ps rows; compiler inserts lgkm waits) ----
        #pragma unroll
        for (int ks = 0; ks < 2; ++ks) {
            bf16x8 pa = *(const bf16x8*)&Ps[q0w + t16][ks * 32 + quad * 8];
            #pragma unroll
            for (int dt = 0; dt < 4; ++dt) {
                bf16x8 vb = *(const bf16x8*)&Vt[dt * 16 + t16][ks * 32 + quad * 8];
                o_acc[dt] = __builtin_amdgcn_mfma_f32_16x16x32_bf16(pa, vb, o_acc[dt], 0, 0, 0);
            }
        }
    }

    // ---- reduce l over the 16 t16 lanes (rows live on fixed quad) ----
    #pragma unroll
    for (int r = 0; r < 4; ++r) {
        #pragma unroll
        for (int off = 1; off < 16; off <<= 1)
            lsum[r] += __shfl_xor(lsum[r], off, 16);
    }

    // ---- epilogue: O[b,s,h*64+d] = o/l; save l ----
    #pragma unroll
    for (int r = 0; r < 4; ++r) {
        const int row = q0 + q0w + quad * 4 + r;
        const float inv = 1.0f / lsum[r];
        #pragma unroll
        for (int dt = 0; dt < 4; ++dt)
            O[((size_t)(b * TS) + row) * TE + h * TD + dt * 16 + t16] = o_acc[dt][r] * inv;
        if (t16 == 0)
            Ls[(size_t)bh * TS + row] = lsum[r];
    }
}

// ----------------------------------------------------------------------------
// attn_avg with MFMA (unchanged)
// ----------------------------------------------------------------------------
__global__ __launch_bounds__(256, 2)
void attn_avg_k(const float* __restrict__ Q, const float* __restrict__ Kg,
                const float* __restrict__ Ls, float* __restrict__ AV)
{
    __shared__ short Qt[128][72];        // [q][d] bf16, Q pre-scaled by 0.125*log2e
    __shared__ short Kt[128][72];        // [j][d] bf16
    __shared__ float ML[TH][128];        // [h][row] = 1/l

    const int tid  = threadIdx.x;
    const int lane = tid & 63;
    const int wv   = tid >> 6;
    const int t16  = lane & 15;
    const int quad = lane >> 4;
    const int wq = (wv >> 1) * 64;
    const int wj = (wv & 1) * 64;

    const int j0 = blockIdx.x * 128;
    const int q0 = blockIdx.y * 128;
    const int b  = blockIdx.z;

    #pragma unroll
    for (int i = 0; i < 8; ++i) {
        const int u = tid + 256 * i;          // 2048
        const int h = u >> 7, r = u & 127;
        ML[h][r] = 1.0f / Ls[(size_t)(b * TH + h) * TS + q0 + r];
    }

    f32x4 acc[4][4];
    #pragma unroll
    for (int mt = 0; mt < 4; ++mt)
        #pragma unroll
        for (int nt = 0; nt < 4; ++nt) acc[mt][nt] = (f32x4){0.f, 0.f, 0.f, 0.f};

    const float qscale = 0.125f * 1.44269504f;

    for (int h = 0; h < TH; ++h) {
        __syncthreads();
        const size_t hoff = (size_t)(b * TH + h) * TS * TD;
        #pragma unroll
        for (int i = 0; i < 8; ++i) {
            const int f = tid + 256 * i;
            const int row = f >> 4;
            const int dq = (f & 15) * 4;
            float4 qv = *(const float4*)(Q + hoff + (size_t)(q0 + row) * TD + dq);
            uint2 qp = make_uint2(pack_rhu(qv.x * qscale, qv.y * qscale),
                                  pack_rhu(qv.z * qscale, qv.w * qscale));
            *(uint2*)&Qt[row][dq] = qp;
            float4 kv = *(const float4*)(Kg + hoff + (size_t)(j0 + row) * TD + dq);
            uint2 kp = make_uint2(pack_rhu(kv.x, kv.y), pack_rhu(kv.z, kv.w));
            *(uint2*)&Kt[row][dq] = kp;
        }
        __syncthreads();

        f32x4 sc[4][4];
        #pragma unroll
        for (int mt = 0; mt < 4; ++mt)
            #pragma unroll
            for (int nt = 0; nt < 4; ++nt) sc[mt][nt] = (f32x4){0.f, 0.f, 0.f, 0.f};
        #pragma unroll
        for (int ks = 0; ks < 2; ++ks) {
            bf16x8 af[4], bf[4];
            #pragma unroll
            for (int mt = 0; mt < 4; ++mt)
                af[mt] = *(const bf16x8*)&Qt[wq + mt * 16 + t16][ks * 32 + quad * 8];
            #pragma unroll
            for (int nt = 0; nt < 4; ++nt)
                bf[nt] = *(const bf16x8*)&Kt[wj + nt * 16 + t16][ks * 32 + quad * 8];
            #pragma unroll
            for (int mt = 0; mt < 4; ++mt)
                #pragma unroll
                for (int nt = 0; nt < 4; ++nt)
                    sc[mt][nt] = __builtin_amdgcn_mfma_f32_16x16x32_bf16(af[mt], bf[nt], sc[mt][nt], 0, 0, 0);
        }

        #pragma unroll
        for (int mt = 0; mt < 4; ++mt) {
            const int rl = wq + mt * 16 + quad * 4;
            const float lv[4] = {ML[h][rl], ML[h][rl + 1], ML[h][rl + 2], ML[h][rl + 3]};
            #pragma unroll
            for (int nt = 0; nt < 4; ++nt)
                #pragma unroll
                for (int r = 0; r < 4; ++r)
                    acc[mt][nt][r] = fmaf(__builtin_amdgcn_exp2f(sc[mt][nt][r]), lv[r], acc[mt][nt][r]);
        }
    }

    const float inv_h = 1.0f / (float)TH;
    #pragma unroll
    for (int mt = 0; mt < 4; ++mt) {
        #pragma unroll
        for (int r = 0; r < 4; ++r) {
            const int row = q0 + wq + mt * 16 + quad * 4 + r;
            #pragma unroll
            for (int nt = 0; nt < 4; ++nt) {
                const int col = j0 + wj + nt * 16 + t16;
                AV[((size_t)b * TS + row) * TS + col] = acc[mt][nt][r] * inv_h;
            }
        }
    }
}

// ----------------------------------------------------------------------------
extern "C" void kernel_launch(void* const* d_in, const int* in_sizes, int n_in,
                              void* d_out, int out_size, void* d_ws, size_t ws_size,
                              hipStream_t stream)
{
    const float* query = (const float*)d_in[0];
    const float* key   = (const float*)d_in[1];
    const float* value = (const float*)d_in[2];
    const float* Wq = (const float*)d_in[3];
    const float* bq = (const float*)d_in[4];
    const float* Wk = (const float*)d_in[5];
    const float* bk = (const float*)d_in[6];
    const float* Wv = (const float*)d_in[7];
    const float* bv = (const float*)d_in[8];
    const float* Wo = (const float*)d_in[9];
    const float* bo = (const float*)d_in[10];

    float* ws  = (float*)d_ws;
    float* Qr  = ws + WS_Q;       // RoPE'd Q fp32 [B,H,S,D]
    float* Kr  = ws + WS_K;       // RoPE'd K fp32 [B,H,S,D]
    float* Lsf = ws + WS_L;       // softmax denominators [B,H,S]
    float* tab = ws + WS_TAB;     // cos/sin

    float* out  = (float*)d_out;                   // [B,S,E]
    float* attn = out + (size_t)TB * TS * TE;      // [B,S,S] (written last)
    // park bf16 V^T and pre-projection O in the attn region (dead by attn_avg)
    short* VT = (short*)attn;                      // bf16 [B,H,D,S] = 4.2M floats
    float* Ow = attn + 4194304;                    // fp32 [B,S,E]   = 8.4M floats

    dim3 blk(256);
    dim3 gproj(TE / 128, TM_ / 128);

    gemm_nt<1><<<gproj, blk, 0, stream>>>(query, Wq, bq, Qr);
    gemm_nt<1><<<gproj, blk, 0, stream>>>(key,   Wk, bk, Kr);
    gemm_nt<2><<<gproj, blk, 0, stream>>>(value, Wv, bv, (float*)VT);
    rope_table<<<dim3(256), blk, 0, stream>>>(tab);
    rope_apply<<<dim3(32768), blk, 0, stream>>>(Qr, Kr, tab);
    attn_flash<<<dim3(TS / 128, TH, TB), dim3(512), 0, stream>>>(Qr, Kr, VT, Ow, Lsf);
    gemm_nt<0><<<gproj, blk, 0, stream>>>(Ow, Wo, bo, out);
    attn_avg_k<<<dim3(TS / 128, TS / 128, TB), blk, 0, stream>>>(Qr, Kr, Lsf, attn);
}